// Round 4
// baseline (643.295 us; speedup 1.0000x reference)
//
#include <hip/hip_runtime.h>

// ---------------------------------------------------------------------------
// RPN forward, MI355X. Only batch element 7 contributes to the output.
// transposeW2 (float2-packed weights) -> conv3x3 v6 (lane=2oc, 25px halves,
// software-pipelined: LDS double-buffer + 1-iteration prefetch distance for
// x rows and weights, 9xb64 weight loads, 8 cin-split partials) ->
// reduce+leaky -> 1x1 heads -> decode/score/key -> O(N^2) rank sort ->
// top-6000 -> NMS bitmask (reference's yy2=max bug replicated) ->
// word-serial scan -> 300x4 boxes. Deterministic fp32: per-accumulator FMA
// chain (cin asc, taps 0..8) bitwise-identical to v3/v5.
// (Round 3: resubmit of v6 — R3 bench was an infra failure, not kernel.)
// ---------------------------------------------------------------------------

#define NPIX 2500      // 50*50
#define NANCH 22500    // 2500*9
#define NKEY 22528     // NANCH padded to 88*256 (sentinel tail)
#define PRE 6000
#define MASKW 94       // ceil(6000/64) usable words
#define MW 96          // storage stride in words
#define JCHUNK 1536    // j-chunk for mask kernel (24 words)
#define CS 8           // cin splits for conv3x3
#define KSLOT 8        // static kept-row load slots per block in scan

// ------- weight transpose+pack: wt(oc, ct) -> wtP[ct][g*128 + 2*l + h] -----
// pair (h=0,1) = (w[g*128+l], w[g*128+64+l]) so conv reads one float2/tap.
__global__ __launch_bounds__(256) void transposeW2(
    const float* __restrict__ wt,   // (512, 4608)
    float* __restrict__ wtP)        // (4608, 512) packed
{
    __shared__ float T[64][65];
    const int tid = threadIdx.x;
    const int c   = tid & 63;
    const int r4  = tid >> 6;
    const int ct0 = blockIdx.x * 64;
    const int ocb = blockIdx.y * 64;
    const int g   = blockIdx.y >> 1;    // 128-oc group
    const int h   = blockIdx.y & 1;     // pair slot
    #pragma unroll
    for (int i = 0; i < 16; ++i) {
        const int o = r4 + i * 4;
        T[o][c] = wt[(size_t)(ocb + o) * 4608 + ct0 + c];
    }
    __syncthreads();
    #pragma unroll
    for (int i = 0; i < 16; ++i) {
        const int ctl = r4 + i * 4;
        wtP[(size_t)(ct0 + ctl) * 512 + g * 128 + 2 * c + h] = T[c][ctl];
    }
}

// ---------------- conv 3x3 v6: pipelined lane=2oc, wave = half row ---------
// grid (4 ocGroups, 100 row-halves, 8 cin groups) = 3200 waves. Per cin:
// 9 coalesced float2 weight loads + 3 x-row loads, ALL issued >=1 iteration
// (~900cy FMA) before use; LDS rows double-buffered (write buf^1 at top,
// read buf written last iteration) -> no intra-iteration latency edges.
// 25 px x 2 oc x 9 taps = 450 FMA. Per-accumulator FMA order bitwise-
// identical to v3/v5 (cin asc, taps 0..8).
__global__ __launch_bounds__(64) void conv3x3_v6(
    const float* __restrict__ x,    // batch-7 base (512,50,50)
    const float* __restrict__ wtP,  // packed (4608, 512)
    float* __restrict__ part)       // (CS, 2500, 512)
{
    __shared__ __align__(16) float sRow[2][3 * 32];  // double-buffered window
    const int lane = threadIdx.x;
    const int g    = blockIdx.x;                 // oc group: ocb = g*128
    const int rh   = blockIdx.y;                 // 0..99
    const int r    = rh >> 1;                    // row 0..49 (wave-uniform)
    const int h    = rh & 1;                     // half 0/1
    const int c0   = h * 25;                     // first output px col
    const int cing = blockIdx.z * 64;

    const float m0 = (r > 0)  ? 1.0f : 0.0f;
    const float m2 = (r < 49) ? 1.0f : 0.0f;
    const int  sr0 = (r > 0)  ? r - 1 : 0;
    const int  sr2 = (r < 49) ? r + 1 : 49;

    // staged col for this lane: global col = c0 - 1 + lane  (lane 0..26)
    const int col  = c0 - 1 + lane;
    const bool cOK = (lane < 27) && (col >= 0) && (col < 50);

    const float2* w2base = (const float2*)wtP + (size_t)cing * 9 * 256 + g * 64 + lane;

    float accA[26], accB[26];
    #pragma unroll
    for (int q = 0; q < 26; ++q) { accA[q] = 0.f; accB[q] = 0.f; }

    // ---- prologue: load cin0 (stage now), issue cin1 prefetch ----
    float2 w[9];
    #pragma unroll
    for (int t = 0; t < 9; ++t) w[t] = w2base[t * 256];
    {
        float v0 = 0.f, v1 = 0.f, v2 = 0.f;
        const float* xp = x + (size_t)cing * NPIX;
        if (cOK) {
            v0 = xp[sr0 * 50 + col] * m0;
            v1 = xp[r   * 50 + col];
            v2 = xp[sr2 * 50 + col] * m2;
        }
        if (lane < 32) {
            sRow[0][0 * 32 + lane] = v0;
            sRow[0][1 * 32 + lane] = v1;
            sRow[0][2 * 32 + lane] = v2;
        }
    }
    float nv0 = 0.f, nv1 = 0.f, nv2 = 0.f;
    if (cOK) {
        const float* xp = x + (size_t)(cing + 1) * NPIX;
        nv0 = xp[sr0 * 50 + col] * m0;
        nv1 = xp[r   * 50 + col];
        nv2 = xp[sr2 * 50 + col] * m2;
    }
    float2 nw[9];
    #pragma unroll
    for (int t = 0; t < 9; ++t) nw[t] = w2base[2304 + t * 256];  // cin1

    for (int cin = 0; cin < 64; ++cin) {
        const int cur = cin & 1;
        // 1) stage cin+1 rows into the other buffer (nv loaded 1 iter ago)
        if (cin < 63 && lane < 32) {
            float* sN = sRow[cur ^ 1];
            sN[0 * 32 + lane] = nv0;
            sN[1 * 32 + lane] = nv1;
            sN[2 * 32 + lane] = nv2;
        }
        // 2) issue x prefetch for cin+2 (full iteration to land)
        if (cin < 62 && cOK) {
            const float* xp = x + (size_t)(cing + cin + 2) * NPIX;
            nv0 = xp[sr0 * 50 + col] * m0;
            nv1 = xp[r   * 50 + col];
            nv2 = xp[sr2 * 50 + col] * m2;
        }

        // 3) compute from sRow[cur] (written 1 iteration ago) with w (= w(cin))
        const float* sB = sRow[cur];
        float wA[9], wB[9];
        #pragma unroll
        for (int t = 0; t < 9; ++t) { wA[t] = w[t].x; wB[t] = w[t].y; }

        const float4* R0 = (const float4*)(sB + 0 * 32);
        const float4* R1 = (const float4*)(sB + 1 * 32);
        const float4* R2 = (const float4*)(sB + 2 * 32);

        float4 q0, q1, q2;
        q0 = q1 = q2 = make_float4(0.f, 0.f, 0.f, 0.f);
        #pragma unroll
        for (int B = 0; B < 7; ++B) {
            const float4 n0 = R0[B];
            const float4 n1 = R1[B];
            const float4 n2 = R2[B];
            if (B > 0) {
                const int p = 4 * B - 2;
                {
                    float a = accA[p], b = accB[p];
                    a = fmaf(wA[0], q0.z, a); a = fmaf(wA[1], q0.w, a); a = fmaf(wA[2], n0.x, a);
                    a = fmaf(wA[3], q1.z, a); a = fmaf(wA[4], q1.w, a); a = fmaf(wA[5], n1.x, a);
                    a = fmaf(wA[6], q2.z, a); a = fmaf(wA[7], q2.w, a); a = fmaf(wA[8], n2.x, a);
                    b = fmaf(wB[0], q0.z, b); b = fmaf(wB[1], q0.w, b); b = fmaf(wB[2], n0.x, b);
                    b = fmaf(wB[3], q1.z, b); b = fmaf(wB[4], q1.w, b); b = fmaf(wB[5], n1.x, b);
                    b = fmaf(wB[6], q2.z, b); b = fmaf(wB[7], q2.w, b); b = fmaf(wB[8], n2.x, b);
                    accA[p] = a; accB[p] = b;
                }
                {
                    float a = accA[p + 1], b = accB[p + 1];
                    a = fmaf(wA[0], q0.w, a); a = fmaf(wA[1], n0.x, a); a = fmaf(wA[2], n0.y, a);
                    a = fmaf(wA[3], q1.w, a); a = fmaf(wA[4], n1.x, a); a = fmaf(wA[5], n1.y, a);
                    a = fmaf(wA[6], q2.w, a); a = fmaf(wA[7], n2.x, a); a = fmaf(wA[8], n2.y, a);
                    b = fmaf(wB[0], q0.w, b); b = fmaf(wB[1], n0.x, b); b = fmaf(wB[2], n0.y, b);
                    b = fmaf(wB[3], q1.w, b); b = fmaf(wB[4], n1.x, b); b = fmaf(wB[5], n1.y, b);
                    b = fmaf(wB[6], q2.w, b); b = fmaf(wB[7], n2.x, b); b = fmaf(wB[8], n2.y, b);
                    accA[p + 1] = a; accB[p + 1] = b;
                }
            }
            {
                const int p = 4 * B;
                {
                    float a = accA[p], b = accB[p];
                    a = fmaf(wA[0], n0.x, a); a = fmaf(wA[1], n0.y, a); a = fmaf(wA[2], n0.z, a);
                    a = fmaf(wA[3], n1.x, a); a = fmaf(wA[4], n1.y, a); a = fmaf(wA[5], n1.z, a);
                    a = fmaf(wA[6], n2.x, a); a = fmaf(wA[7], n2.y, a); a = fmaf(wA[8], n2.z, a);
                    b = fmaf(wB[0], n0.x, b); b = fmaf(wB[1], n0.y, b); b = fmaf(wB[2], n0.z, b);
                    b = fmaf(wB[3], n1.x, b); b = fmaf(wB[4], n1.y, b); b = fmaf(wB[5], n1.z, b);
                    b = fmaf(wB[6], n2.x, b); b = fmaf(wB[7], n2.y, b); b = fmaf(wB[8], n2.z, b);
                    accA[p] = a; accB[p] = b;
                }
                {
                    float a = accA[p + 1], b = accB[p + 1];
                    a = fmaf(wA[0], n0.y, a); a = fmaf(wA[1], n0.z, a); a = fmaf(wA[2], n0.w, a);
                    a = fmaf(wA[3], n1.y, a); a = fmaf(wA[4], n1.z, a); a = fmaf(wA[5], n1.w, a);
                    a = fmaf(wA[6], n2.y, a); a = fmaf(wA[7], n2.z, a); a = fmaf(wA[8], n2.w, a);
                    b = fmaf(wB[0], n0.y, b); b = fmaf(wB[1], n0.z, b); b = fmaf(wB[2], n0.w, b);
                    b = fmaf(wB[3], n1.y, b); b = fmaf(wB[4], n1.z, b); b = fmaf(wB[5], n1.w, b);
                    b = fmaf(wB[6], n2.y, b); b = fmaf(wB[7], n2.z, b); b = fmaf(wB[8], n2.w, b);
                    accA[p + 1] = a; accB[p + 1] = b;
                }
            }
            q0 = n0; q1 = n1; q2 = n2;
        }

        // 4) rotate weights; issue weight prefetch for cin+2
        if (cin < 63) {
            #pragma unroll
            for (int t = 0; t < 9; ++t) w[t] = nw[t];
            if (cin < 62) {
                const float2* wn = w2base + (size_t)(cin + 2) * 2304;
                #pragma unroll
                for (int t = 0; t < 9; ++t) nw[t] = wn[t * 256];
            }
        }
    }

    // write px c0..c0+24 (q=25 extra acc is discarded; h=1 owns px 25..49)
    float* dst = part + ((size_t)blockIdx.z * NPIX + r * 50 + c0) * 512 + g * 128 + lane;
    #pragma unroll
    for (int q = 0; q < 25; ++q) {
        dst[(size_t)q * 512]      = accA[q];
        dst[(size_t)q * 512 + 64] = accB[q];
    }
}

// ---------------- reduce partials + bias + leaky + transpose ---------------
__global__ __launch_bounds__(256) void reduce_leaky(
    const float* __restrict__ part, const float* __restrict__ bias,
    float* __restrict__ feat)
{
    __shared__ float T[64][65];
    const int tid = threadIdx.x;
    const int o   = tid & 63;
    const int r4  = tid >> 6;
    const int pt  = blockIdx.x;
    const int ocb = blockIdx.y * 64;
    const float b = bias[ocb + o];
    #pragma unroll
    for (int i = 0; i < 16; ++i) {
        const int pl = r4 + i * 4;
        const int px = pt * 64 + pl;
        if (px < NPIX) {
            float s = 0.f;
            #pragma unroll
            for (int k = 0; k < CS; ++k)
                s += part[((size_t)k * NPIX + px) * 512 + ocb + o];
            s += b;
            s = (s >= 0.f) ? s : 0.01f * s;
            T[pl][o] = s;
        }
    }
    __syncthreads();
    const int pl = tid & 63;
    const int px = pt * 64 + pl;
    if (px < NPIX) {
        #pragma unroll
        for (int i = 0; i < 16; ++i) {
            const int ocl = r4 + i * 4;
            feat[(size_t)(ocb + ocl) * NPIX + px] = T[pl][ocl];
        }
    }
}

// ---------------- 1x1 heads: 4-wave cin split + LDS tree reduce ------------
__global__ __launch_bounds__(256) void conv1x1_heads(
    const float* __restrict__ feat,
    const float* __restrict__ rw, const float* __restrict__ rb,
    const float* __restrict__ cw, const float* __restrict__ cb,
    float* __restrict__ regcls)   // (54, 2500)
{
    __shared__ float sAcc[3][18][64];
    const int tid  = threadIdx.x;
    const int lane = tid & 63;
    const int wv   = tid >> 6;
    const int pix0 = blockIdx.x * 64 + lane;
    const bool act = (pix0 < NPIX);
    const int pix  = act ? pix0 : (NPIX - 1);
    const int chunk = blockIdx.y;
    const float* wb; const float* bb; int ocbase;
    if (chunk == 0)      { wb = rw;            bb = rb;      ocbase = 0;  }
    else if (chunk == 1) { wb = rw + 18 * 512; bb = rb + 18; ocbase = 18; }
    else                 { wb = cw;            bb = cb;      ocbase = 36; }

    float acc[18];
    #pragma unroll
    for (int k = 0; k < 18; ++k) acc[k] = 0.f;

    const int c0 = wv * 128;
    for (int cin = c0; cin < c0 + 128; ++cin) {
        const float v = feat[(size_t)cin * NPIX + pix];
        #pragma unroll
        for (int k = 0; k < 18; ++k)
            acc[k] = fmaf(wb[k * 512 + cin], v, acc[k]);
    }
    if (wv > 0) {
        #pragma unroll
        for (int k = 0; k < 18; ++k) sAcc[wv - 1][k][lane] = acc[k];
    }
    __syncthreads();
    if (wv == 0 && act) {
        #pragma unroll
        for (int k = 0; k < 18; ++k) {
            float s = acc[k];
            s += sAcc[0][k][lane];
            s += sAcc[1][k][lane];
            s += sAcc[2][k][lane];
            regcls[(size_t)(ocbase + k) * NPIX + pix] = s + bb[k];
        }
    }
}

// ---------------- decode: anchors, softmax score, sortable key -------------
__global__ __launch_bounds__(256) void decodeK(
    const float* __restrict__ regcls,
    float4* __restrict__ boxes,
    unsigned long long* __restrict__ keys)
{
    const int i = blockIdx.x * 256 + threadIdx.x;
    if (i >= NANCH) {
        if (i < NKEY) keys[i] = 0xFFFFFFFFFFFFFFFFull;  // sentinel: > all keys
        return;
    }
    const int pos = i / 9;
    const int a   = i - pos * 9;
    const int hh  = pos / 50;
    const int wwp = pos - hh * 50;
    const int r = a / 3, s = a - r * 3;

    const float base_s[3] = {128.f, 256.f, 512.f};
    const float sq [3] = {0.70710678118654752440f, 1.0f, 1.41421356237309504880f};
    const float sqi[3] = {1.41421356237309504880f, 1.0f, 0.70710678118654752440f};
    const float hs = base_s[s] * sq[r];
    const float ws = base_s[s] * sqi[r];
    const float cx = (float)(hh * 16 + 8);    // cx indexed by h (reference quirk)
    const float cy = (float)(wwp * 16 + 8);
    const float ax = cx - ws * 0.5f;
    const float ay = cy - hs * 0.5f;

    const float pr0 = regcls[(size_t)(a * 4 + 0) * NPIX + pos];
    const float pr1 = regcls[(size_t)(a * 4 + 1) * NPIX + pos];
    const float pr2 = regcls[(size_t)(a * 4 + 2) * NPIX + pos];
    const float pr3 = regcls[(size_t)(a * 4 + 3) * NPIX + pos];
    const float c0  = regcls[(size_t)(36 + a * 2 + 0) * NPIX + pos];
    const float c1  = regcls[(size_t)(36 + a * 2 + 1) * NPIX + pos];

    const float m  = fmaxf(c0, c1);
    const float e0 = expf(c0 - m);
    const float e1 = expf(c1 - m);
    const float score = e1 / (e0 + e1);

    const float t0 = pr0 + ax;
    const float t1 = pr1 + ay;
    const float hi = 799.0f;
    const float rx1 = fminf(fmaxf(t0, 0.f), hi);
    const float ry1 = fminf(fmaxf(t1, 0.f), hi);
    const float rx2 = fminf(fmaxf((t0 + pr2) + ws, 0.f), hi);
    const float ry2 = fminf(fmaxf((t1 + pr3) + hs, 0.f), hi);
    const float bw = pr2 + ws;
    const float bh = pr3 + hs;
    const bool valid = (bw >= 16.f) && (bh >= 16.f);
    const float sc = valid ? score : -__builtin_inff();

    unsigned u = __float_as_uint(sc);
    u = (u & 0x80000000u) ? ~u : (u | 0x80000000u);  // monotone ascending map
    const unsigned k32 = ~u;                          // descending score
    keys[i]  = ((unsigned long long)k32 << 32) | (unsigned)i;  // tie: asc index
    boxes[i] = make_float4(rx1, ry1, rx2, ry2);
}

// ---------------- O(N^2) rank (stable argsort position) --------------------
__global__ __launch_bounds__(256) void rankK(
    const unsigned long long* __restrict__ keys, int* __restrict__ rank)
{
    const int i = blockIdx.x * 256 + threadIdx.x;
    const unsigned long long my = (i < NANCH) ? keys[i] : 0ull;
    const unsigned long long* kj = keys + blockIdx.y * 2816;
    int cnt = 0;
    for (int t = 0; t < 2816; t += 8) {
        #pragma unroll
        for (int q = 0; q < 8; ++q)
            cnt += (kj[t + q] < my) ? 1 : 0;
    }
    if (i < NANCH) atomicAdd(&rank[i], cnt);
}

__global__ __launch_bounds__(256) void scatterK(
    const float4* __restrict__ boxes, const int* __restrict__ rank,
    float4* __restrict__ sboxes)
{
    const int i = blockIdx.x * 256 + threadIdx.x;
    if (i < NANCH) {
        const int r = rank[i];
        if (r < PRE) sboxes[r] = boxes[i];
    }
}

// ---------------- NMS suppression bitmask (reference bug replicated) -------
__global__ __launch_bounds__(256) void nmsMaskK(
    const float4* __restrict__ sb, unsigned long long* __restrict__ mask)
{
    __shared__ float sx1[JCHUNK], sy1[JCHUNK], sx2[JCHUNK], sy2[JCHUNK], sar[JCHUNK];
    const int tid = threadIdx.x;
    const int jbase = blockIdx.y * JCHUNK;
    for (int t = tid; t < JCHUNK; t += 256) {
        const int j = jbase + t;
        if (j < PRE) {
            const float4 b = sb[j];
            sx1[t] = b.x; sy1[t] = b.y; sx2[t] = b.z; sy2[t] = b.w;
            sar[t] = (b.z - b.x + 1.f) * (b.w - b.y + 1.f);
        } else {
            sx1[t] = 0.f; sy1[t] = 0.f; sx2[t] = -1.f; sy2[t] = 0.f; sar[t] = 0.f;
        }
    }
    __syncthreads();
    const int i = blockIdx.x * 16 + (tid >> 4);
    const float4 bi = sb[i];
    const float x1 = bi.x, y1 = bi.y, x2 = bi.z, y2 = bi.w;
    const float ar = (x2 - x1 + 1.f) * (y2 - y1 + 1.f);
    for (int w = (tid & 15); w < 24; w += 16) {
        unsigned long long bits = 0ull;
        const int l0 = w * 64;
        for (int u = 0; u < 64; ++u) {
            const int j = jbase + l0 + u;
            if (j > i && j < PRE) {
                const int l = l0 + u;
                const float xx1 = fmaxf(x1, sx1[l]);
                const float yy1 = fmaxf(y1, sy1[l]);
                const float xx2 = fminf(x2, sx2[l]);
                const float yy2 = fmaxf(y2, sy2[l]);        // reference bug: max
                const float wv = fmaxf(0.f, xx2 - xx1 + 1.f);
                const float hv = fmaxf(0.f, yy2 - yy1 + 1.f);
                const float inter = wv * hv;
                const float ov = inter / ((ar + sar[l]) - inter);  // precise div
                if (ov > 0.7f) bits |= (1ull << u);
            }
        }
        mask[(size_t)i * MW + blockIdx.y * 24 + w] = bits;
    }
}

// ---------------- word-serial NMS scan + output (single wave) --------------
// Per 64-candidate block g: (1) pure-ALU in-block loop using ONLY the diag
// word (every iteration keeps exactly one box; suppression via diag
// readlanes); (2) batched loads of the ~3 actually-kept rows (<=KSLOT static
// slots + rare overflow), one wait, OR into register-resident rem.
__global__ __launch_bounds__(64) void nmsScanOutK(
    const unsigned long long* __restrict__ mask,
    const float4* __restrict__ sb,
    float* __restrict__ out)
{
    __shared__ int sKept[300];
    __shared__ unsigned long long sKeepW[MASKW];
    const int lane = threadIdx.x;

    unsigned long long rem0 = 0ull, rem1 = 0ull;   // lane l: words l, 64+l
    int cnt = 0;
    int done = 0;

    unsigned long long diag = mask[(size_t)lane * MW + 0];   // block 0 diag

    for (int g = 0; g < MASKW && !done; ++g) {
        // prefetch next block's diagonal word (overlaps this block's work)
        unsigned long long diag_next = 0ull;
        if (g + 1 < MASKW) {
            const int r2 = (g + 1) * 64 + lane;
            if (r2 < PRE) diag_next = mask[(size_t)r2 * MW + (g + 1)];
        }
        // initial suppression word for this block (broadcast from rem)
        unsigned long long cur;
        {
            unsigned lo, hi;
            if (g < 64) {
                lo = __builtin_amdgcn_readlane((unsigned)rem0, g);
                hi = __builtin_amdgcn_readlane((unsigned)(rem0 >> 32), g);
            } else {
                lo = __builtin_amdgcn_readlane((unsigned)rem1, g - 64);
                hi = __builtin_amdgcn_readlane((unsigned)(rem1 >> 32), g - 64);
            }
            cur = ((unsigned long long)hi << 32) | lo;
        }
        const unsigned long long valid =
            (g == MASKW - 1) ? 0x0000FFFFFFFFFFFFull : ~0ull;   // 48 tail bits

        // ---- in-block serial loop: pure ALU, zero memory ops ----
        unsigned long long kb = 0ull;
        for (;;) {
            const unsigned long long nd = (~cur) & valid;
            if (!nd) break;
            const int b = __builtin_ctzll(nd);     // unsuppressed => KEPT
            if (lane == 0 && cnt < 300) sKept[cnt] = g * 64 + b;
            ++cnt;
            kb |= (1ull << b);
            if (cnt >= 300) { done = 1; break; }
            const unsigned dlo = __builtin_amdgcn_readlane((unsigned)diag, b);
            const unsigned dhi = __builtin_amdgcn_readlane((unsigned)(diag >> 32), b);
            cur |= (1ull << b) | (((unsigned long long)dhi << 32) | dlo);
        }
        if (lane == 0) sKeepW[g] = kb;

        // ---- batched kept-row loads: OR their full rows into rem ----
        if (!done && kb) {
            int kbit[KSLOT];
            unsigned long long t = kb;
            #pragma unroll
            for (int s = 0; s < KSLOT; ++s) {
                kbit[s] = t ? __builtin_ctzll(t) : 64;
                t &= t - 1;
            }
            unsigned long long a0 = 0ull, a1 = 0ull;
            #pragma unroll
            for (int s = 0; s < KSLOT; ++s) {
                if (kbit[s] < 64) {                // wave-uniform branch
                    const unsigned long long* pr =
                        mask + (size_t)(g * 64 + kbit[s]) * MW;
                    a0 |= pr[lane];
                    a1 |= (lane < MASKW - 64) ? pr[64 + lane] : 0ull;
                }
            }
            while (t) {                             // >KSLOT overflow (rare)
                const int b = __builtin_ctzll(t); t &= t - 1;
                const unsigned long long* pr = mask + (size_t)(g * 64 + b) * MW;
                a0 |= pr[lane];
                a1 |= (lane < MASKW - 64) ? pr[64 + lane] : 0ull;
            }
            rem0 |= a0;
            rem1 |= a1;
        }
        diag = diag_next;
    }

    __syncthreads();

    if (cnt < 300) {                                 // filler: unkept, asc index
        int c = cnt;
        for (int g = 0; g < MASKW && c < 300; ++g) {
            const unsigned long long valid =
                (g == MASKW - 1) ? 0x0000FFFFFFFFFFFFull : ~0ull;
            unsigned long long u = (~sKeepW[g]) & valid;
            while (u && c < 300) {
                const int b = __builtin_ctzll(u); u &= u - 1;
                if (lane == 0) sKept[c] = g * 64 + b;
                ++c;
            }
        }
    }
    __syncthreads();

    for (int s = lane; s < 300; s += 64) {
        const float4 b = sb[sKept[s]];
        out[s * 4 + 0] = b.x;
        out[s * 4 + 1] = b.y;
        out[s * 4 + 2] = b.z - b.x + 1.0f;
        out[s * 4 + 3] = b.w - b.y + 1.0f;
    }
}

// ---------------------------------------------------------------------------
extern "C" void kernel_launch(void* const* d_in, const int* in_sizes, int n_in,
                              void* d_out, int out_size, void* d_ws, size_t ws_size,
                              hipStream_t stream)
{
    (void)in_sizes; (void)n_in; (void)out_size; (void)ws_size;
    const float* x   = (const float*)d_in[0] + (size_t)7 * 512 * NPIX; // batch 7
    const float* cw3 = (const float*)d_in[1];
    const float* cb3 = (const float*)d_in[2];
    const float* rw  = (const float*)d_in[3];
    const float* rb  = (const float*)d_in[4];
    const float* clw = (const float*)d_in[5];
    const float* clb = (const float*)d_in[6];
    float* out = (float*)d_out;

    char* p = (char*)d_ws;
    auto alloc = [&](size_t n) { char* r = p; p += (n + 255) & ~(size_t)255; return r; };
    float*  part   = (float*)alloc((size_t)CS * NPIX * 512 * 4);  // 41 MB
    float*  wtP    = (float*)alloc((size_t)4608 * 512 * 4);       // 9.4 MB
    float*  feat   = (float*)alloc((size_t)512 * NPIX * 4);       // 5.12 MB
    float*  regcls = (float*)alloc((size_t)54 * NPIX * 4);        // 0.54 MB
    float4* boxes  = (float4*)alloc((size_t)NANCH * 16);          // 0.36 MB
    unsigned long long* keys = (unsigned long long*)alloc((size_t)NKEY * 8);
    int*    rank   = (int*)alloc((size_t)NANCH * 4);
    float4* sboxes = (float4*)alloc((size_t)PRE * 16);
    unsigned long long* mask = (unsigned long long*)alloc((size_t)PRE * MW * 8); // 4.6 MB

    hipMemsetAsync(rank, 0, (size_t)NANCH * 4, stream);
    transposeW2   <<<dim3(72, 8), 256, 0, stream>>>(cw3, wtP);
    conv3x3_v6    <<<dim3(4, 100, CS), 64, 0, stream>>>(x, wtP, part);
    reduce_leaky  <<<dim3(40, 8), 256, 0, stream>>>(part, cb3, feat);
    conv1x1_heads <<<dim3(40, 3), 256, 0, stream>>>(feat, rw, rb, clw, clb, regcls);
    decodeK       <<<88, 256, 0, stream>>>(regcls, boxes, keys);
    rankK         <<<dim3(88, 8), 256, 0, stream>>>(keys, rank);
    scatterK      <<<88, 256, 0, stream>>>(boxes, rank, sboxes);
    nmsMaskK      <<<dim3(375, 4), 256, 0, stream>>>(sboxes, mask);
    nmsScanOutK   <<<1, 64, 0, stream>>>(mask, sboxes, out);
}

// Round 5
// 614.747 us; speedup vs baseline: 1.0464x; 1.0464x over previous
//
#include <hip/hip_runtime.h>

// ---------------------------------------------------------------------------
// RPN forward, MI355X. Only batch element 7 contributes to the output.
// transposeW3 (weights -> (cin, ocg, tap, 8oc) for SGPR broadcast) ->
// conv3x3 v7 (lane = PIXEL, 8 oc/wave, per-lane 3x3 window in VGPRs,
// wave-uniform weights via scalar loads, NO LDS, 32-waves/CU occupancy,
// 8 cin-split partials) -> reduce+leaky -> 1x1 heads -> decode/score/key ->
// O(N^2) rank sort -> top-6000 -> NMS bitmask (reference's yy2=max bug
// replicated) -> word-serial scan -> 300x4 boxes. Deterministic fp32:
// per-accumulator FMA chain (cin asc, taps 0..8) bitwise-identical to v3.
// ---------------------------------------------------------------------------

#define NPIX 2500      // 50*50
#define NANCH 22500    // 2500*9
#define NKEY 22528     // NANCH padded to 88*256 (sentinel tail)
#define PRE 6000
#define MASKW 94       // ceil(6000/64) usable words
#define MW 96          // storage stride in words
#define JCHUNK 1536    // j-chunk for mask kernel (24 words)
#define CS 8           // cin splits for conv3x3
#define KSLOT 8        // static kept-row load slots per block in scan

// ------- weight transform: wt(oc, cin*9+t) -> wtV[cin][ocg][t][j] ----------
// wtV[((cin*64 + ocg)*9 + t)*8 + j] = wt[ocg*8+j][cin*9+t]; conv reads 72
// floats per (cin, ocg) through a wave-uniform pointer (-> s_load / SGPRs).
__global__ __launch_bounds__(256) void transposeW3(
    const float* __restrict__ wt,   // (512, 4608)
    float* __restrict__ wtV)        // (512, 64, 9, 8)
{
    __shared__ float T[64][65];
    const int tid = threadIdx.x;
    const int cidx = tid & 63;
    const int r4  = tid >> 6;
    const int ct0 = blockIdx.x * 64;
    const int ocb = blockIdx.y * 64;
    #pragma unroll
    for (int i = 0; i < 16; ++i) {
        const int o = r4 + i * 4;
        T[o][cidx] = wt[(size_t)(ocb + o) * 4608 + ct0 + cidx];
    }
    __syncthreads();
    #pragma unroll
    for (int i = 0; i < 16; ++i) {
        const int ctl = ct0 + r4 + i * 4;
        const int cin = ctl / 9;
        const int t   = ctl - cin * 9;
        const int oc  = ocb + cidx;
        wtV[(((size_t)cin * 64 + (oc >> 3)) * 9 + t) * 8 + (oc & 7)] =
            T[cidx][r4 + i * 4];
    }
}

// ---------------- conv 3x3 v7: lane = pixel, 8 oc per wave, no LDS ---------
// grid (64 ocGroups, 40 pxBlocks, 8 cin groups) = 20480 waves, ~58 VGPR ->
// full 32-waves/CU occupancy. Per cin: 9 per-lane window loads (prefetched
// 1 cin ahead, registers only), 9 mask muls, 72 FMA with SGPR weights.
// Per-accumulator FMA order bitwise-identical to v3 (cin asc, taps 0..8).
__global__ __launch_bounds__(64) void conv3x3_v7(
    const float* __restrict__ x,    // batch-7 base (512,50,50)
    const float* __restrict__ wtV,  // (512, 64, 9, 8)
    float* __restrict__ part)       // (CS, 2500, 512)
{
    const int lane = threadIdx.x;
    const int ocg  = blockIdx.x;            // 0..63 -> oc = ocg*8 + j
    const int pb   = blockIdx.y;            // 0..39
    const int cing = blockIdx.z * 64;
    const int px   = pb * 64 + lane;
    const bool act = (px < NPIX);
    const int pxc  = act ? px : 0;
    const int r    = pxc / 50;
    const int c    = pxc - r * 50;

    // per-lane 3x3 window: clamped offsets + 0/1 masks (computed once)
    int   off[9];
    float msk[9];
    #pragma unroll
    for (int dr = -1; dr <= 1; ++dr) {
        #pragma unroll
        for (int dc = -1; dc <= 1; ++dc) {
            const int t  = (dr + 1) * 3 + (dc + 1);
            const int rr = r + dr, cc = c + dc;
            const bool ok = act && (rr >= 0) && (rr < 50) && (cc >= 0) && (cc < 50);
            const int rcl = rr < 0 ? 0 : (rr > 49 ? 49 : rr);
            const int ccl = cc < 0 ? 0 : (cc > 49 ? 49 : cc);
            off[t] = rcl * 50 + ccl;
            msk[t] = ok ? 1.0f : 0.0f;
        }
    }

    float acc[8];
    #pragma unroll
    for (int j = 0; j < 8; ++j) acc[j] = 0.f;

    // prefetch window for cin=0
    float nv[9];
    {
        const float* xb = x + (size_t)cing * NPIX;
        #pragma unroll
        for (int t = 0; t < 9; ++t) nv[t] = xb[off[t]];
    }

    const float* wbase = wtV + ((size_t)cing * 64 + ocg) * 72;

    for (int cin = 0; cin < 64; ++cin) {
        // consume prefetched window (apply pad masks)
        float v[9];
        #pragma unroll
        for (int t = 0; t < 9; ++t) v[t] = nv[t] * msk[t];

        // issue next-cin window loads (land during the 72-FMA block)
        if (cin < 63) {
            const float* xb = x + (size_t)(cing + cin + 1) * NPIX;
            #pragma unroll
            for (int t = 0; t < 9; ++t) nv[t] = xb[off[t]];
        }

        // weights: wave-uniform pointer -> scalar loads (SGPR operand in FMA)
        const float* wp = wbase + (size_t)cin * 64 * 72;
        #pragma unroll
        for (int j = 0; j < 8; ++j) {
            float a = acc[j];
            #pragma unroll
            for (int t = 0; t < 9; ++t)
                a = fmaf(wp[t * 8 + j], v[t], a);
            acc[j] = a;
        }
    }

    if (act) {
        float* dst = part + ((size_t)blockIdx.z * NPIX + px) * 512 + ocg * 8;
        *(float4*)(dst)     = make_float4(acc[0], acc[1], acc[2], acc[3]);
        *(float4*)(dst + 4) = make_float4(acc[4], acc[5], acc[6], acc[7]);
    }
}

// ---------------- reduce partials + bias + leaky + transpose ---------------
__global__ __launch_bounds__(256) void reduce_leaky(
    const float* __restrict__ part, const float* __restrict__ bias,
    float* __restrict__ feat)
{
    __shared__ float T[64][65];
    const int tid = threadIdx.x;
    const int o   = tid & 63;
    const int r4  = tid >> 6;
    const int pt  = blockIdx.x;
    const int ocb = blockIdx.y * 64;
    const float b = bias[ocb + o];
    #pragma unroll
    for (int i = 0; i < 16; ++i) {
        const int pl = r4 + i * 4;
        const int px = pt * 64 + pl;
        if (px < NPIX) {
            float s = 0.f;
            #pragma unroll
            for (int k = 0; k < CS; ++k)
                s += part[((size_t)k * NPIX + px) * 512 + ocb + o];
            s += b;
            s = (s >= 0.f) ? s : 0.01f * s;
            T[pl][o] = s;
        }
    }
    __syncthreads();
    const int pl = tid & 63;
    const int px = pt * 64 + pl;
    if (px < NPIX) {
        #pragma unroll
        for (int i = 0; i < 16; ++i) {
            const int ocl = r4 + i * 4;
            feat[(size_t)(ocb + ocl) * NPIX + px] = T[pl][ocl];
        }
    }
}

// ---------------- 1x1 heads: 4-wave cin split + LDS tree reduce ------------
__global__ __launch_bounds__(256) void conv1x1_heads(
    const float* __restrict__ feat,
    const float* __restrict__ rw, const float* __restrict__ rb,
    const float* __restrict__ cw, const float* __restrict__ cb,
    float* __restrict__ regcls)   // (54, 2500)
{
    __shared__ float sAcc[3][18][64];
    const int tid  = threadIdx.x;
    const int lane = tid & 63;
    const int wv   = tid >> 6;
    const int pix0 = blockIdx.x * 64 + lane;
    const bool act = (pix0 < NPIX);
    const int pix  = act ? pix0 : (NPIX - 1);
    const int chunk = blockIdx.y;
    const float* wb; const float* bb; int ocbase;
    if (chunk == 0)      { wb = rw;            bb = rb;      ocbase = 0;  }
    else if (chunk == 1) { wb = rw + 18 * 512; bb = rb + 18; ocbase = 18; }
    else                 { wb = cw;            bb = cb;      ocbase = 36; }

    float acc[18];
    #pragma unroll
    for (int k = 0; k < 18; ++k) acc[k] = 0.f;

    const int c0 = wv * 128;
    for (int cin = c0; cin < c0 + 128; ++cin) {
        const float v = feat[(size_t)cin * NPIX + pix];
        #pragma unroll
        for (int k = 0; k < 18; ++k)
            acc[k] = fmaf(wb[k * 512 + cin], v, acc[k]);
    }
    if (wv > 0) {
        #pragma unroll
        for (int k = 0; k < 18; ++k) sAcc[wv - 1][k][lane] = acc[k];
    }
    __syncthreads();
    if (wv == 0 && act) {
        #pragma unroll
        for (int k = 0; k < 18; ++k) {
            float s = acc[k];
            s += sAcc[0][k][lane];
            s += sAcc[1][k][lane];
            s += sAcc[2][k][lane];
            regcls[(size_t)(ocbase + k) * NPIX + pix] = s + bb[k];
        }
    }
}

// ---------------- decode: anchors, softmax score, sortable key -------------
__global__ __launch_bounds__(256) void decodeK(
    const float* __restrict__ regcls,
    float4* __restrict__ boxes,
    unsigned long long* __restrict__ keys)
{
    const int i = blockIdx.x * 256 + threadIdx.x;
    if (i >= NANCH) {
        if (i < NKEY) keys[i] = 0xFFFFFFFFFFFFFFFFull;  // sentinel: > all keys
        return;
    }
    const int pos = i / 9;
    const int a   = i - pos * 9;
    const int hh  = pos / 50;
    const int wwp = pos - hh * 50;
    const int r = a / 3, s = a - r * 3;

    const float base_s[3] = {128.f, 256.f, 512.f};
    const float sq [3] = {0.70710678118654752440f, 1.0f, 1.41421356237309504880f};
    const float sqi[3] = {1.41421356237309504880f, 1.0f, 0.70710678118654752440f};
    const float hs = base_s[s] * sq[r];
    const float ws = base_s[s] * sqi[r];
    const float cx = (float)(hh * 16 + 8);    // cx indexed by h (reference quirk)
    const float cy = (float)(wwp * 16 + 8);
    const float ax = cx - ws * 0.5f;
    const float ay = cy - hs * 0.5f;

    const float pr0 = regcls[(size_t)(a * 4 + 0) * NPIX + pos];
    const float pr1 = regcls[(size_t)(a * 4 + 1) * NPIX + pos];
    const float pr2 = regcls[(size_t)(a * 4 + 2) * NPIX + pos];
    const float pr3 = regcls[(size_t)(a * 4 + 3) * NPIX + pos];
    const float c0  = regcls[(size_t)(36 + a * 2 + 0) * NPIX + pos];
    const float c1  = regcls[(size_t)(36 + a * 2 + 1) * NPIX + pos];

    const float m  = fmaxf(c0, c1);
    const float e0 = expf(c0 - m);
    const float e1 = expf(c1 - m);
    const float score = e1 / (e0 + e1);

    const float t0 = pr0 + ax;
    const float t1 = pr1 + ay;
    const float hi = 799.0f;
    const float rx1 = fminf(fmaxf(t0, 0.f), hi);
    const float ry1 = fminf(fmaxf(t1, 0.f), hi);
    const float rx2 = fminf(fmaxf((t0 + pr2) + ws, 0.f), hi);
    const float ry2 = fminf(fmaxf((t1 + pr3) + hs, 0.f), hi);
    const float bw = pr2 + ws;
    const float bh = pr3 + hs;
    const bool valid = (bw >= 16.f) && (bh >= 16.f);
    const float sc = valid ? score : -__builtin_inff();

    unsigned u = __float_as_uint(sc);
    u = (u & 0x80000000u) ? ~u : (u | 0x80000000u);  // monotone ascending map
    const unsigned k32 = ~u;                          // descending score
    keys[i]  = ((unsigned long long)k32 << 32) | (unsigned)i;  // tie: asc index
    boxes[i] = make_float4(rx1, ry1, rx2, ry2);
}

// ---------------- O(N^2) rank (stable argsort position) --------------------
__global__ __launch_bounds__(256) void rankK(
    const unsigned long long* __restrict__ keys, int* __restrict__ rank)
{
    const int i = blockIdx.x * 256 + threadIdx.x;
    const unsigned long long my = (i < NANCH) ? keys[i] : 0ull;
    const unsigned long long* kj = keys + blockIdx.y * 2816;
    int cnt = 0;
    for (int t = 0; t < 2816; t += 8) {
        #pragma unroll
        for (int q = 0; q < 8; ++q)
            cnt += (kj[t + q] < my) ? 1 : 0;
    }
    if (i < NANCH) atomicAdd(&rank[i], cnt);
}

__global__ __launch_bounds__(256) void scatterK(
    const float4* __restrict__ boxes, const int* __restrict__ rank,
    float4* __restrict__ sboxes)
{
    const int i = blockIdx.x * 256 + threadIdx.x;
    if (i < NANCH) {
        const int r = rank[i];
        if (r < PRE) sboxes[r] = boxes[i];
    }
}

// ---------------- NMS suppression bitmask (reference bug replicated) -------
__global__ __launch_bounds__(256) void nmsMaskK(
    const float4* __restrict__ sb, unsigned long long* __restrict__ mask)
{
    __shared__ float sx1[JCHUNK], sy1[JCHUNK], sx2[JCHUNK], sy2[JCHUNK], sar[JCHUNK];
    const int tid = threadIdx.x;
    const int jbase = blockIdx.y * JCHUNK;
    for (int t = tid; t < JCHUNK; t += 256) {
        const int j = jbase + t;
        if (j < PRE) {
            const float4 b = sb[j];
            sx1[t] = b.x; sy1[t] = b.y; sx2[t] = b.z; sy2[t] = b.w;
            sar[t] = (b.z - b.x + 1.f) * (b.w - b.y + 1.f);
        } else {
            sx1[t] = 0.f; sy1[t] = 0.f; sx2[t] = -1.f; sy2[t] = 0.f; sar[t] = 0.f;
        }
    }
    __syncthreads();
    const int i = blockIdx.x * 16 + (tid >> 4);
    const float4 bi = sb[i];
    const float x1 = bi.x, y1 = bi.y, x2 = bi.z, y2 = bi.w;
    const float ar = (x2 - x1 + 1.f) * (y2 - y1 + 1.f);
    for (int w = (tid & 15); w < 24; w += 16) {
        unsigned long long bits = 0ull;
        const int l0 = w * 64;
        for (int u = 0; u < 64; ++u) {
            const int j = jbase + l0 + u;
            if (j > i && j < PRE) {
                const int l = l0 + u;
                const float xx1 = fmaxf(x1, sx1[l]);
                const float yy1 = fmaxf(y1, sy1[l]);
                const float xx2 = fminf(x2, sx2[l]);
                const float yy2 = fmaxf(y2, sy2[l]);        // reference bug: max
                const float wv = fmaxf(0.f, xx2 - xx1 + 1.f);
                const float hv = fmaxf(0.f, yy2 - yy1 + 1.f);
                const float inter = wv * hv;
                const float ov = inter / ((ar + sar[l]) - inter);  // precise div
                if (ov > 0.7f) bits |= (1ull << u);
            }
        }
        mask[(size_t)i * MW + blockIdx.y * 24 + w] = bits;
    }
}

// ---------------- word-serial NMS scan + output (single wave) --------------
// Per 64-candidate block g: (1) pure-ALU in-block loop using ONLY the diag
// word (every iteration keeps exactly one box; suppression via diag
// readlanes); (2) batched loads of the ~3 actually-kept rows (<=KSLOT static
// slots + rare overflow), one wait, OR into register-resident rem.
__global__ __launch_bounds__(64) void nmsScanOutK(
    const unsigned long long* __restrict__ mask,
    const float4* __restrict__ sb,
    float* __restrict__ out)
{
    __shared__ int sKept[300];
    __shared__ unsigned long long sKeepW[MASKW];
    const int lane = threadIdx.x;

    unsigned long long rem0 = 0ull, rem1 = 0ull;   // lane l: words l, 64+l
    int cnt = 0;
    int done = 0;

    unsigned long long diag = mask[(size_t)lane * MW + 0];   // block 0 diag

    for (int g = 0; g < MASKW && !done; ++g) {
        // prefetch next block's diagonal word (overlaps this block's work)
        unsigned long long diag_next = 0ull;
        if (g + 1 < MASKW) {
            const int r2 = (g + 1) * 64 + lane;
            if (r2 < PRE) diag_next = mask[(size_t)r2 * MW + (g + 1)];
        }
        // initial suppression word for this block (broadcast from rem)
        unsigned long long cur;
        {
            unsigned lo, hi;
            if (g < 64) {
                lo = __builtin_amdgcn_readlane((unsigned)rem0, g);
                hi = __builtin_amdgcn_readlane((unsigned)(rem0 >> 32), g);
            } else {
                lo = __builtin_amdgcn_readlane((unsigned)rem1, g - 64);
                hi = __builtin_amdgcn_readlane((unsigned)(rem1 >> 32), g - 64);
            }
            cur = ((unsigned long long)hi << 32) | lo;
        }
        const unsigned long long valid =
            (g == MASKW - 1) ? 0x0000FFFFFFFFFFFFull : ~0ull;   // 48 tail bits

        // ---- in-block serial loop: pure ALU, zero memory ops ----
        unsigned long long kb = 0ull;
        for (;;) {
            const unsigned long long nd = (~cur) & valid;
            if (!nd) break;
            const int b = __builtin_ctzll(nd);     // unsuppressed => KEPT
            if (lane == 0 && cnt < 300) sKept[cnt] = g * 64 + b;
            ++cnt;
            kb |= (1ull << b);
            if (cnt >= 300) { done = 1; break; }
            const unsigned dlo = __builtin_amdgcn_readlane((unsigned)diag, b);
            const unsigned dhi = __builtin_amdgcn_readlane((unsigned)(diag >> 32), b);
            cur |= (1ull << b) | (((unsigned long long)dhi << 32) | dlo);
        }
        if (lane == 0) sKeepW[g] = kb;

        // ---- batched kept-row loads: OR their full rows into rem ----
        if (!done && kb) {
            int kbit[KSLOT];
            unsigned long long t = kb;
            #pragma unroll
            for (int s = 0; s < KSLOT; ++s) {
                kbit[s] = t ? __builtin_ctzll(t) : 64;
                t &= t - 1;
            }
            unsigned long long a0 = 0ull, a1 = 0ull;
            #pragma unroll
            for (int s = 0; s < KSLOT; ++s) {
                if (kbit[s] < 64) {                // wave-uniform branch
                    const unsigned long long* pr =
                        mask + (size_t)(g * 64 + kbit[s]) * MW;
                    a0 |= pr[lane];
                    a1 |= (lane < MASKW - 64) ? pr[64 + lane] : 0ull;
                }
            }
            while (t) {                             // >KSLOT overflow (rare)
                const int b = __builtin_ctzll(t); t &= t - 1;
                const unsigned long long* pr = mask + (size_t)(g * 64 + b) * MW;
                a0 |= pr[lane];
                a1 |= (lane < MASKW - 64) ? pr[64 + lane] : 0ull;
            }
            rem0 |= a0;
            rem1 |= a1;
        }
        diag = diag_next;
    }

    __syncthreads();

    if (cnt < 300) {                                 // filler: unkept, asc index
        int c = cnt;
        for (int g = 0; g < MASKW && c < 300; ++g) {
            const unsigned long long valid =
                (g == MASKW - 1) ? 0x0000FFFFFFFFFFFFull : ~0ull;
            unsigned long long u = (~sKeepW[g]) & valid;
            while (u && c < 300) {
                const int b = __builtin_ctzll(u); u &= u - 1;
                if (lane == 0) sKept[c] = g * 64 + b;
                ++c;
            }
        }
    }
    __syncthreads();

    for (int s = lane; s < 300; s += 64) {
        const float4 b = sb[sKept[s]];
        out[s * 4 + 0] = b.x;
        out[s * 4 + 1] = b.y;
        out[s * 4 + 2] = b.z - b.x + 1.0f;
        out[s * 4 + 3] = b.w - b.y + 1.0f;
    }
}

// ---------------------------------------------------------------------------
extern "C" void kernel_launch(void* const* d_in, const int* in_sizes, int n_in,
                              void* d_out, int out_size, void* d_ws, size_t ws_size,
                              hipStream_t stream)
{
    (void)in_sizes; (void)n_in; (void)out_size; (void)ws_size;
    const float* x   = (const float*)d_in[0] + (size_t)7 * 512 * NPIX; // batch 7
    const float* cw3 = (const float*)d_in[1];
    const float* cb3 = (const float*)d_in[2];
    const float* rw  = (const float*)d_in[3];
    const float* rb  = (const float*)d_in[4];
    const float* clw = (const float*)d_in[5];
    const float* clb = (const float*)d_in[6];
    float* out = (float*)d_out;

    char* p = (char*)d_ws;
    auto alloc = [&](size_t n) { char* r = p; p += (n + 255) & ~(size_t)255; return r; };
    float*  part   = (float*)alloc((size_t)CS * NPIX * 512 * 4);  // 41 MB
    float*  wtV    = (float*)alloc((size_t)4608 * 512 * 4);       // 9.4 MB
    float*  feat   = (float*)alloc((size_t)512 * NPIX * 4);       // 5.12 MB
    float*  regcls = (float*)alloc((size_t)54 * NPIX * 4);        // 0.54 MB
    float4* boxes  = (float4*)alloc((size_t)NANCH * 16);          // 0.36 MB
    unsigned long long* keys = (unsigned long long*)alloc((size_t)NKEY * 8);
    int*    rank   = (int*)alloc((size_t)NANCH * 4);
    float4* sboxes = (float4*)alloc((size_t)PRE * 16);
    unsigned long long* mask = (unsigned long long*)alloc((size_t)PRE * MW * 8); // 4.6 MB

    hipMemsetAsync(rank, 0, (size_t)NANCH * 4, stream);
    transposeW3   <<<dim3(72, 8), 256, 0, stream>>>(cw3, wtV);
    conv3x3_v7    <<<dim3(64, 40, CS), 64, 0, stream>>>(x, wtV, part);
    reduce_leaky  <<<dim3(40, 8), 256, 0, stream>>>(part, cb3, feat);
    conv1x1_heads <<<dim3(40, 3), 256, 0, stream>>>(feat, rw, rb, clw, clb, regcls);
    decodeK       <<<88, 256, 0, stream>>>(regcls, boxes, keys);
    rankK         <<<dim3(88, 8), 256, 0, stream>>>(keys, rank);
    scatterK      <<<88, 256, 0, stream>>>(boxes, rank, sboxes);
    nmsMaskK      <<<dim3(375, 4), 256, 0, stream>>>(sboxes, mask);
    nmsScanOutK   <<<1, 64, 0, stream>>>(mask, sboxes, out);
}

// Round 6
// 597.155 us; speedup vs baseline: 1.0773x; 1.0295x over previous
//
#include <hip/hip_runtime.h>

// ---------------------------------------------------------------------------
// RPN forward, MI355X. Only batch element 7 contributes to the output.
// padX (512x52x52 zero-padded input) + transposeW3 (weights -> SGPR layout)
// -> conv3x3 v8 (lane = PIXEL, 8 oc/wave, 256-thr blocks, per-lane window
// loads with IMMEDIATE tap offsets (no masks), A/B register double-buffer,
// wave-uniform weights via s_load, NO LDS, 8 cin-split partials in
// (CS,512,2500) coalesced layout) -> reduce_leaky2 (coalesced, no LDS) ->
// 1x1 heads -> decode/score/key -> O(N^2) rank sort -> top-6000 ->
// NMS bitmask (reference's yy2=max bug replicated) -> word-serial scan ->
// 300x4 boxes. Deterministic fp32: per-accumulator FMA chain (cin asc,
// taps 0..8) and CS reduce order bitwise-identical to v3..v7.
// ---------------------------------------------------------------------------

#define NPIX 2500      // 50*50
#define NANCH 22500    // 2500*9
#define NKEY 22528     // NANCH padded to 88*256 (sentinel tail)
#define PRE 6000
#define MASKW 94       // ceil(6000/64) usable words
#define MW 96          // storage stride in words
#define JCHUNK 1536    // j-chunk for mask kernel (24 words)
#define CS 8           // cin splits for conv3x3
#define KSLOT 8        // static kept-row load slots per block in scan
#define PW 52          // padded width
#define PSL 2704       // 52*52 padded slice

// ---------------- zero-pad input: x(512,50,50) -> xpad(512,52,52) ----------
__global__ __launch_bounds__(256) void padX(
    const float* __restrict__ x, float* __restrict__ xpad)
{
    const int cin = blockIdx.x;
    const float* src = x + (size_t)cin * NPIX;
    float* dst = xpad + (size_t)cin * PSL;
    for (int i = threadIdx.x; i < PSL; i += 256) {
        const int pr = i / PW;
        const int pc = i - pr * PW;
        float v = 0.f;
        if (pr >= 1 && pr <= 50 && pc >= 1 && pc <= 50)
            v = src[(pr - 1) * 50 + (pc - 1)];
        dst[i] = v;
    }
}

// ------- weight transform: wt(oc, cin*9+t) -> wtV[cin][ocg][t][j] ----------
// wtV[((cin*64 + ocg)*9 + t)*8 + j] = wt[ocg*8+j][cin*9+t]; conv reads 72
// floats per (cin, ocg) through a wave-uniform pointer (-> s_load / SGPRs).
__global__ __launch_bounds__(256) void transposeW3(
    const float* __restrict__ wt,   // (512, 4608)
    float* __restrict__ wtV)        // (512, 64, 9, 8)
{
    __shared__ float T[64][65];
    const int tid = threadIdx.x;
    const int cidx = tid & 63;
    const int r4  = tid >> 6;
    const int ct0 = blockIdx.x * 64;
    const int ocb = blockIdx.y * 64;
    #pragma unroll
    for (int i = 0; i < 16; ++i) {
        const int o = r4 + i * 4;
        T[o][cidx] = wt[(size_t)(ocb + o) * 4608 + ct0 + cidx];
    }
    __syncthreads();
    #pragma unroll
    for (int i = 0; i < 16; ++i) {
        const int ctl = ct0 + r4 + i * 4;
        const int cin = ctl / 9;
        const int t   = ctl - cin * 9;
        const int oc  = ocb + cidx;
        wtV[(((size_t)cin * 64 + (oc >> 3)) * 9 + t) * 8 + (oc & 7)] =
            T[cidx][r4 + i * 4];
    }
}

// ---------------- conv 3x3 v8: lane = pixel, padded input, no LDS ----------
// grid (64 ocGroups, 10 pxQuads, 8 cin groups) x 256 thr = 20480 waves in
// 5120 workgroups (4 waves/WG lifts the WG-slot occupancy cap). Per cin:
// 9 loads at immediate tap offsets (A/B reg double-buffer, distance-1
// prefetch, no masks, no per-tap addr math) + 72 FMA with SGPR weights.
// Per-accumulator FMA order bitwise-identical to v3..v7 (cin asc, taps 0..8).
__global__ __launch_bounds__(256) void conv3x3_v8(
    const float* __restrict__ xpad, // padded batch-7 (512,52,52)
    const float* __restrict__ wtV,  // (512, 64, 9, 8)
    float* __restrict__ part2)      // (CS, 512, 2500)
{
    const int tid  = threadIdx.x;
    const int lane = tid & 63;
    const int wv   = tid >> 6;
    const int ocg  = blockIdx.x;            // 0..63 -> oc = ocg*8 + j
    const int pb   = blockIdx.y * 4 + wv;   // 0..39
    const int cing = blockIdx.z * 64;
    const int px   = pb * 64 + lane;
    const bool act = (px < NPIX);
    const int pxc  = act ? px : 0;
    const int r    = pxc / 50;
    const int c    = pxc - r * 50;

    // per-lane padded center address; taps are compile-time offsets
    const float* xb = xpad + (size_t)cing * PSL + (r + 1) * PW + (c + 1);

    float acc[8];
    #pragma unroll
    for (int j = 0; j < 8; ++j) acc[j] = 0.f;

    // A/B window double-buffer, distance-1 prefetch
    float nvA[9], nvB[9];
    #pragma unroll
    for (int t = 0; t < 9; ++t) {
        const int dr = t / 3 - 1, dc = t % 3 - 1;
        nvA[t] = xb[dr * PW + dc];
        nvB[t] = xb[PSL + dr * PW + dc];
    }

    const float* wbase = wtV + ((size_t)cing * 64 + ocg) * 72;

    for (int cin = 0; cin < 64; cin += 2) {
        {   // even cin: consume A
            const float* wp = wbase + (size_t)cin * 4608;   // 64*72
            #pragma unroll
            for (int j = 0; j < 8; ++j) {
                float a = acc[j];
                #pragma unroll
                for (int t = 0; t < 9; ++t)
                    a = fmaf(wp[t * 8 + j], nvA[t], a);
                acc[j] = a;
            }
        }
        if (cin + 2 < 64) {                 // refill A for cin+2
            const float* xn = xb + (size_t)(cin + 2) * PSL;
            #pragma unroll
            for (int t = 0; t < 9; ++t) {
                const int dr = t / 3 - 1, dc = t % 3 - 1;
                nvA[t] = xn[dr * PW + dc];
            }
        }
        {   // odd cin: consume B
            const float* wp = wbase + (size_t)(cin + 1) * 4608;
            #pragma unroll
            for (int j = 0; j < 8; ++j) {
                float a = acc[j];
                #pragma unroll
                for (int t = 0; t < 9; ++t)
                    a = fmaf(wp[t * 8 + j], nvB[t], a);
                acc[j] = a;
            }
        }
        if (cin + 3 < 64) {                 // refill B for cin+3
            const float* xn = xb + (size_t)(cin + 3) * PSL;
            #pragma unroll
            for (int t = 0; t < 9; ++t) {
                const int dr = t / 3 - 1, dc = t % 3 - 1;
                nvB[t] = xn[dr * PW + dc];
            }
        }
    }

    if (act) {   // coalesced: lane=px contiguous per oc row
        float* dst = part2 + ((size_t)blockIdx.z * 512 + ocg * 8) * NPIX + px;
        #pragma unroll
        for (int j = 0; j < 8; ++j)
            dst[(size_t)j * NPIX] = acc[j];
    }
}

// ---------------- reduce partials + bias + leaky (coalesced) ---------------
__global__ __launch_bounds__(256) void reduce_leaky2(
    const float* __restrict__ part2, const float* __restrict__ bias,
    float* __restrict__ feat)
{
    const int oc = blockIdx.y;
    const int px = blockIdx.x * 256 + threadIdx.x;
    if (px >= NPIX) return;
    float s = 0.f;
    #pragma unroll
    for (int k = 0; k < CS; ++k)
        s += part2[((size_t)k * 512 + oc) * NPIX + px];
    s += bias[oc];
    s = (s >= 0.f) ? s : 0.01f * s;
    feat[(size_t)oc * NPIX + px] = s;
}

// ---------------- 1x1 heads: 4-wave cin split + LDS tree reduce ------------
__global__ __launch_bounds__(256) void conv1x1_heads(
    const float* __restrict__ feat,
    const float* __restrict__ rw, const float* __restrict__ rb,
    const float* __restrict__ cw, const float* __restrict__ cb,
    float* __restrict__ regcls)   // (54, 2500)
{
    __shared__ float sAcc[3][18][64];
    const int tid  = threadIdx.x;
    const int lane = tid & 63;
    const int wv   = tid >> 6;
    const int pix0 = blockIdx.x * 64 + lane;
    const bool act = (pix0 < NPIX);
    const int pix  = act ? pix0 : (NPIX - 1);
    const int chunk = blockIdx.y;
    const float* wb; const float* bb; int ocbase;
    if (chunk == 0)      { wb = rw;            bb = rb;      ocbase = 0;  }
    else if (chunk == 1) { wb = rw + 18 * 512; bb = rb + 18; ocbase = 18; }
    else                 { wb = cw;            bb = cb;      ocbase = 36; }

    float acc[18];
    #pragma unroll
    for (int k = 0; k < 18; ++k) acc[k] = 0.f;

    const int c0 = wv * 128;
    for (int cin = c0; cin < c0 + 128; ++cin) {
        const float v = feat[(size_t)cin * NPIX + pix];
        #pragma unroll
        for (int k = 0; k < 18; ++k)
            acc[k] = fmaf(wb[k * 512 + cin], v, acc[k]);
    }
    if (wv > 0) {
        #pragma unroll
        for (int k = 0; k < 18; ++k) sAcc[wv - 1][k][lane] = acc[k];
    }
    __syncthreads();
    if (wv == 0 && act) {
        #pragma unroll
        for (int k = 0; k < 18; ++k) {
            float s = acc[k];
            s += sAcc[0][k][lane];
            s += sAcc[1][k][lane];
            s += sAcc[2][k][lane];
            regcls[(size_t)(ocbase + k) * NPIX + pix] = s + bb[k];
        }
    }
}

// ---------------- decode: anchors, softmax score, sortable key -------------
__global__ __launch_bounds__(256) void decodeK(
    const float* __restrict__ regcls,
    float4* __restrict__ boxes,
    unsigned long long* __restrict__ keys)
{
    const int i = blockIdx.x * 256 + threadIdx.x;
    if (i >= NANCH) {
        if (i < NKEY) keys[i] = 0xFFFFFFFFFFFFFFFFull;  // sentinel: > all keys
        return;
    }
    const int pos = i / 9;
    const int a   = i - pos * 9;
    const int hh  = pos / 50;
    const int wwp = pos - hh * 50;
    const int r = a / 3, s = a - r * 3;

    const float base_s[3] = {128.f, 256.f, 512.f};
    const float sq [3] = {0.70710678118654752440f, 1.0f, 1.41421356237309504880f};
    const float sqi[3] = {1.41421356237309504880f, 1.0f, 0.70710678118654752440f};
    const float hs = base_s[s] * sq[r];
    const float ws = base_s[s] * sqi[r];
    const float cx = (float)(hh * 16 + 8);    // cx indexed by h (reference quirk)
    const float cy = (float)(wwp * 16 + 8);
    const float ax = cx - ws * 0.5f;
    const float ay = cy - hs * 0.5f;

    const float pr0 = regcls[(size_t)(a * 4 + 0) * NPIX + pos];
    const float pr1 = regcls[(size_t)(a * 4 + 1) * NPIX + pos];
    const float pr2 = regcls[(size_t)(a * 4 + 2) * NPIX + pos];
    const float pr3 = regcls[(size_t)(a * 4 + 3) * NPIX + pos];
    const float c0  = regcls[(size_t)(36 + a * 2 + 0) * NPIX + pos];
    const float c1  = regcls[(size_t)(36 + a * 2 + 1) * NPIX + pos];

    const float m  = fmaxf(c0, c1);
    const float e0 = expf(c0 - m);
    const float e1 = expf(c1 - m);
    const float score = e1 / (e0 + e1);

    const float t0 = pr0 + ax;
    const float t1 = pr1 + ay;
    const float hi = 799.0f;
    const float rx1 = fminf(fmaxf(t0, 0.f), hi);
    const float ry1 = fminf(fmaxf(t1, 0.f), hi);
    const float rx2 = fminf(fmaxf((t0 + pr2) + ws, 0.f), hi);
    const float ry2 = fminf(fmaxf((t1 + pr3) + hs, 0.f), hi);
    const float bw = pr2 + ws;
    const float bh = pr3 + hs;
    const bool valid = (bw >= 16.f) && (bh >= 16.f);
    const float sc = valid ? score : -__builtin_inff();

    unsigned u = __float_as_uint(sc);
    u = (u & 0x80000000u) ? ~u : (u | 0x80000000u);  // monotone ascending map
    const unsigned k32 = ~u;                          // descending score
    keys[i]  = ((unsigned long long)k32 << 32) | (unsigned)i;  // tie: asc index
    boxes[i] = make_float4(rx1, ry1, rx2, ry2);
}

// ---------------- O(N^2) rank (stable argsort position) --------------------
__global__ __launch_bounds__(256) void rankK(
    const unsigned long long* __restrict__ keys, int* __restrict__ rank)
{
    const int i = blockIdx.x * 256 + threadIdx.x;
    const unsigned long long my = (i < NANCH) ? keys[i] : 0ull;
    const unsigned long long* kj = keys + blockIdx.y * 2816;
    int cnt = 0;
    for (int t = 0; t < 2816; t += 8) {
        #pragma unroll
        for (int q = 0; q < 8; ++q)
            cnt += (kj[t + q] < my) ? 1 : 0;
    }
    if (i < NANCH) atomicAdd(&rank[i], cnt);
}

__global__ __launch_bounds__(256) void scatterK(
    const float4* __restrict__ boxes, const int* __restrict__ rank,
    float4* __restrict__ sboxes)
{
    const int i = blockIdx.x * 256 + threadIdx.x;
    if (i < NANCH) {
        const int r = rank[i];
        if (r < PRE) sboxes[r] = boxes[i];
    }
}

// ---------------- NMS suppression bitmask (reference bug replicated) -------
__global__ __launch_bounds__(256) void nmsMaskK(
    const float4* __restrict__ sb, unsigned long long* __restrict__ mask)
{
    __shared__ float sx1[JCHUNK], sy1[JCHUNK], sx2[JCHUNK], sy2[JCHUNK], sar[JCHUNK];
    const int tid = threadIdx.x;
    const int jbase = blockIdx.y * JCHUNK;
    for (int t = tid; t < JCHUNK; t += 256) {
        const int j = jbase + t;
        if (j < PRE) {
            const float4 b = sb[j];
            sx1[t] = b.x; sy1[t] = b.y; sx2[t] = b.z; sy2[t] = b.w;
            sar[t] = (b.z - b.x + 1.f) * (b.w - b.y + 1.f);
        } else {
            sx1[t] = 0.f; sy1[t] = 0.f; sx2[t] = -1.f; sy2[t] = 0.f; sar[t] = 0.f;
        }
    }
    __syncthreads();
    const int i = blockIdx.x * 16 + (tid >> 4);
    const float4 bi = sb[i];
    const float x1 = bi.x, y1 = bi.y, x2 = bi.z, y2 = bi.w;
    const float ar = (x2 - x1 + 1.f) * (y2 - y1 + 1.f);
    for (int w = (tid & 15); w < 24; w += 16) {
        unsigned long long bits = 0ull;
        const int l0 = w * 64;
        for (int u = 0; u < 64; ++u) {
            const int j = jbase + l0 + u;
            if (j > i && j < PRE) {
                const int l = l0 + u;
                const float xx1 = fmaxf(x1, sx1[l]);
                const float yy1 = fmaxf(y1, sy1[l]);
                const float xx2 = fminf(x2, sx2[l]);
                const float yy2 = fmaxf(y2, sy2[l]);        // reference bug: max
                const float wv = fmaxf(0.f, xx2 - xx1 + 1.f);
                const float hv = fmaxf(0.f, yy2 - yy1 + 1.f);
                const float inter = wv * hv;
                const float ov = inter / ((ar + sar[l]) - inter);  // precise div
                if (ov > 0.7f) bits |= (1ull << u);
            }
        }
        mask[(size_t)i * MW + blockIdx.y * 24 + w] = bits;
    }
}

// ---------------- word-serial NMS scan + output (single wave) --------------
// Per 64-candidate block g: (1) pure-ALU in-block loop using ONLY the diag
// word (every iteration keeps exactly one box; suppression via diag
// readlanes); (2) batched loads of the ~3 actually-kept rows (<=KSLOT static
// slots + rare overflow), one wait, OR into register-resident rem.
__global__ __launch_bounds__(64) void nmsScanOutK(
    const unsigned long long* __restrict__ mask,
    const float4* __restrict__ sb,
    float* __restrict__ out)
{
    __shared__ int sKept[300];
    __shared__ unsigned long long sKeepW[MASKW];
    const int lane = threadIdx.x;

    unsigned long long rem0 = 0ull, rem1 = 0ull;   // lane l: words l, 64+l
    int cnt = 0;
    int done = 0;

    unsigned long long diag = mask[(size_t)lane * MW + 0];   // block 0 diag

    for (int g = 0; g < MASKW && !done; ++g) {
        // prefetch next block's diagonal word (overlaps this block's work)
        unsigned long long diag_next = 0ull;
        if (g + 1 < MASKW) {
            const int r2 = (g + 1) * 64 + lane;
            if (r2 < PRE) diag_next = mask[(size_t)r2 * MW + (g + 1)];
        }
        // initial suppression word for this block (broadcast from rem)
        unsigned long long cur;
        {
            unsigned lo, hi;
            if (g < 64) {
                lo = __builtin_amdgcn_readlane((unsigned)rem0, g);
                hi = __builtin_amdgcn_readlane((unsigned)(rem0 >> 32), g);
            } else {
                lo = __builtin_amdgcn_readlane((unsigned)rem1, g - 64);
                hi = __builtin_amdgcn_readlane((unsigned)(rem1 >> 32), g - 64);
            }
            cur = ((unsigned long long)hi << 32) | lo;
        }
        const unsigned long long valid =
            (g == MASKW - 1) ? 0x0000FFFFFFFFFFFFull : ~0ull;   // 48 tail bits

        // ---- in-block serial loop: pure ALU, zero memory ops ----
        unsigned long long kb = 0ull;
        for (;;) {
            const unsigned long long nd = (~cur) & valid;
            if (!nd) break;
            const int b = __builtin_ctzll(nd);     // unsuppressed => KEPT
            if (lane == 0 && cnt < 300) sKept[cnt] = g * 64 + b;
            ++cnt;
            kb |= (1ull << b);
            if (cnt >= 300) { done = 1; break; }
            const unsigned dlo = __builtin_amdgcn_readlane((unsigned)diag, b);
            const unsigned dhi = __builtin_amdgcn_readlane((unsigned)(diag >> 32), b);
            cur |= (1ull << b) | (((unsigned long long)dhi << 32) | dlo);
        }
        if (lane == 0) sKeepW[g] = kb;

        // ---- batched kept-row loads: OR their full rows into rem ----
        if (!done && kb) {
            int kbit[KSLOT];
            unsigned long long t = kb;
            #pragma unroll
            for (int s = 0; s < KSLOT; ++s) {
                kbit[s] = t ? __builtin_ctzll(t) : 64;
                t &= t - 1;
            }
            unsigned long long a0 = 0ull, a1 = 0ull;
            #pragma unroll
            for (int s = 0; s < KSLOT; ++s) {
                if (kbit[s] < 64) {                // wave-uniform branch
                    const unsigned long long* pr =
                        mask + (size_t)(g * 64 + kbit[s]) * MW;
                    a0 |= pr[lane];
                    a1 |= (lane < MASKW - 64) ? pr[64 + lane] : 0ull;
                }
            }
            while (t) {                             // >KSLOT overflow (rare)
                const int b = __builtin_ctzll(t); t &= t - 1;
                const unsigned long long* pr = mask + (size_t)(g * 64 + b) * MW;
                a0 |= pr[lane];
                a1 |= (lane < MASKW - 64) ? pr[64 + lane] : 0ull;
            }
            rem0 |= a0;
            rem1 |= a1;
        }
        diag = diag_next;
    }

    __syncthreads();

    if (cnt < 300) {                                 // filler: unkept, asc index
        int c = cnt;
        for (int g = 0; g < MASKW && c < 300; ++g) {
            const unsigned long long valid =
                (g == MASKW - 1) ? 0x0000FFFFFFFFFFFFull : ~0ull;
            unsigned long long u = (~sKeepW[g]) & valid;
            while (u && c < 300) {
                const int b = __builtin_ctzll(u); u &= u - 1;
                if (lane == 0) sKept[c] = g * 64 + b;
                ++c;
            }
        }
    }
    __syncthreads();

    for (int s = lane; s < 300; s += 64) {
        const float4 b = sb[sKept[s]];
        out[s * 4 + 0] = b.x;
        out[s * 4 + 1] = b.y;
        out[s * 4 + 2] = b.z - b.x + 1.0f;
        out[s * 4 + 3] = b.w - b.y + 1.0f;
    }
}

// ---------------------------------------------------------------------------
extern "C" void kernel_launch(void* const* d_in, const int* in_sizes, int n_in,
                              void* d_out, int out_size, void* d_ws, size_t ws_size,
                              hipStream_t stream)
{
    (void)in_sizes; (void)n_in; (void)out_size; (void)ws_size;
    const float* x   = (const float*)d_in[0] + (size_t)7 * 512 * NPIX; // batch 7
    const float* cw3 = (const float*)d_in[1];
    const float* cb3 = (const float*)d_in[2];
    const float* rw  = (const float*)d_in[3];
    const float* rb  = (const float*)d_in[4];
    const float* clw = (const float*)d_in[5];
    const float* clb = (const float*)d_in[6];
    float* out = (float*)d_out;

    char* p = (char*)d_ws;
    auto alloc = [&](size_t n) { char* r = p; p += (n + 255) & ~(size_t)255; return r; };
    float*  part2  = (float*)alloc((size_t)CS * 512 * NPIX * 4);  // 41 MB
    float*  wtV    = (float*)alloc((size_t)4608 * 512 * 4);       // 9.4 MB
    float*  xpad   = (float*)alloc((size_t)512 * PSL * 4);        // 5.5 MB
    float*  feat   = (float*)alloc((size_t)512 * NPIX * 4);       // 5.12 MB
    float*  regcls = (float*)alloc((size_t)54 * NPIX * 4);        // 0.54 MB
    float4* boxes  = (float4*)alloc((size_t)NANCH * 16);          // 0.36 MB
    unsigned long long* keys = (unsigned long long*)alloc((size_t)NKEY * 8);
    int*    rank   = (int*)alloc((size_t)NANCH * 4);
    float4* sboxes = (float4*)alloc((size_t)PRE * 16);
    unsigned long long* mask = (unsigned long long*)alloc((size_t)PRE * MW * 8); // 4.6 MB

    hipMemsetAsync(rank, 0, (size_t)NANCH * 4, stream);
    padX          <<<512, 256, 0, stream>>>(x, xpad);
    transposeW3   <<<dim3(72, 8), 256, 0, stream>>>(cw3, wtV);
    conv3x3_v8    <<<dim3(64, 10, CS), 256, 0, stream>>>(xpad, wtV, part2);
    reduce_leaky2 <<<dim3(10, 512), 256, 0, stream>>>(part2, cb3, feat);
    conv1x1_heads <<<dim3(40, 3), 256, 0, stream>>>(feat, rw, rb, clw, clb, regcls);
    decodeK       <<<88, 256, 0, stream>>>(regcls, boxes, keys);
    rankK         <<<dim3(88, 8), 256, 0, stream>>>(keys, rank);
    scatterK      <<<88, 256, 0, stream>>>(boxes, rank, sboxes);
    nmsMaskK      <<<dim3(375, 4), 256, 0, stream>>>(sboxes, mask);
    nmsScanOutK   <<<1, 64, 0, stream>>>(mask, sboxes, out);
}

// Round 7
// 575.569 us; speedup vs baseline: 1.1177x; 1.0375x over previous
//
#include <hip/hip_runtime.h>

// ---------------------------------------------------------------------------
// RPN forward, MI355X. Only batch element 7 contributes to the output.
// prepK (fused: zero-pad input 512x52x52 + weight->SGPR-layout transpose) ->
// conv3x3 v9 (lane = PIXEL, 2 px/thread (px, px+1280) amortizing the 72
// per-cin weight s_loads over 144 FMAs, 8 oc/wave, immediate tap offsets,
// NO LDS, 8 cin-split partials in (CS,512,2500) coalesced layout) ->
// reduce_leaky2 -> 1x1 heads -> decode/score/key -> O(N^2) rank sort ->
// top-6000 -> NMS bitmask (reference's yy2=max bug replicated) ->
// word-serial scan -> 300x4 boxes. Deterministic fp32: per-accumulator FMA
// chain (cin asc, taps 0..8) and CS reduce order bitwise-identical to v3..v8.
// ---------------------------------------------------------------------------

#define NPIX 2500      // 50*50
#define NANCH 22500    // 2500*9
#define NKEY 22528     // NANCH padded to 88*256 (sentinel tail)
#define PRE 6000
#define MASKW 94       // ceil(6000/64) usable words
#define MW 96          // storage stride in words
#define JCHUNK 1536    // j-chunk for mask kernel (24 words)
#define CS 8           // cin splits for conv3x3
#define KSLOT 8        // static kept-row load slots per block in scan
#define PW 52          // padded width
#define PSL 2704       // 52*52 padded slice

// ------ fused prep: blocks 0..511 zero-pad x; blocks 512..1087 transpose w -
// wtV[((cin*64 + ocg)*9 + t)*8 + j] = wt[ocg*8+j][cin*9+t]
__global__ __launch_bounds__(256) void prepK(
    const float* __restrict__ x,    // batch-7 base (512,50,50)
    const float* __restrict__ wt,   // (512, 4608)
    float* __restrict__ xpad,       // (512, 52, 52)
    float* __restrict__ wtV)        // (512, 64, 9, 8)
{
    __shared__ float T[64][65];
    const int bx = blockIdx.x;
    if (bx < 512) {
        const int cin = bx;
        const float* src = x + (size_t)cin * NPIX;
        float* dst = xpad + (size_t)cin * PSL;
        for (int i = threadIdx.x; i < PSL; i += 256) {
            const int pr = i / PW;
            const int pc = i - pr * PW;
            float v = 0.f;
            if (pr >= 1 && pr <= 50 && pc >= 1 && pc <= 50)
                v = src[(pr - 1) * 50 + (pc - 1)];
            dst[i] = v;
        }
        return;
    }
    const int idx  = bx - 512;           // 0..575 = 72 x 8
    const int ct0  = (idx % 72) * 64;
    const int ocb  = (idx / 72) * 64;
    const int tid  = threadIdx.x;
    const int cidx = tid & 63;
    const int r4   = tid >> 6;
    #pragma unroll
    for (int i = 0; i < 16; ++i) {
        const int o = r4 + i * 4;
        T[o][cidx] = wt[(size_t)(ocb + o) * 4608 + ct0 + cidx];
    }
    __syncthreads();
    #pragma unroll
    for (int i = 0; i < 16; ++i) {
        const int ctl = ct0 + r4 + i * 4;
        const int cin = ctl / 9;
        const int t   = ctl - cin * 9;
        const int oc  = ocb + cidx;
        wtV[(((size_t)cin * 64 + (oc >> 3)) * 9 + t) * 8 + (oc & 7)] =
            T[cidx][r4 + i * 4];
    }
}

// ---------------- conv 3x3 v9: 2 pixels/thread, padded input, no LDS -------
// grid (64 ocGroups, 5 pxOcts, 8 cin groups) x 256 thr = 10240 waves.
// Per cin: 18 loads at immediate tap offsets + 144 FMA sharing ONE batch of
// 72 SGPR weights (2x amortization of the s_load lgkm wait vs v8).
// Per-accumulator FMA order bitwise-identical to v3..v8 (cin asc, taps 0..8).
__global__ __launch_bounds__(256) void conv3x3_v9(
    const float* __restrict__ xpad, // padded batch-7 (512,52,52)
    const float* __restrict__ wtV,  // (512, 64, 9, 8)
    float* __restrict__ part2)      // (CS, 512, 2500)
{
    const int tid  = threadIdx.x;
    const int lane = tid & 63;
    const int wv   = tid >> 6;
    const int ocg  = blockIdx.x;            // 0..63 -> oc = ocg*8 + j
    const int pb   = blockIdx.y * 4 + wv;   // 0..19
    const int cing = blockIdx.z * 64;
    const int px0  = pb * 64 + lane;        // 0..1279 (always valid)
    const int px1  = px0 + 1280;            // 1280..2559
    const bool act1 = (px1 < NPIX);
    const int r0 = px0 / 50, cc0 = px0 - r0 * 50;
    const int px1c = act1 ? px1 : 0;
    const int r1 = px1c / 50, cc1 = px1c - r1 * 50;

    // per-lane padded center addresses; taps are compile-time offsets
    const float* xb0 = xpad + (size_t)cing * PSL + (r0 + 1) * PW + (cc0 + 1);
    const float* xb1 = xpad + (size_t)cing * PSL + (r1 + 1) * PW + (cc1 + 1);

    float acc0[8], acc1[8];
    #pragma unroll
    for (int j = 0; j < 8; ++j) { acc0[j] = 0.f; acc1[j] = 0.f; }

    const float* wbase = wtV + ((size_t)cing * 64 + ocg) * 72;

    for (int cin = 0; cin < 64; ++cin) {
        float v0[9], v1[9];
        const float* xa = xb0 + (size_t)cin * PSL;
        const float* xc = xb1 + (size_t)cin * PSL;
        #pragma unroll
        for (int t = 0; t < 9; ++t) {
            const int dr = t / 3 - 1, dc = t % 3 - 1;
            v0[t] = xa[dr * PW + dc];
            v1[t] = xc[dr * PW + dc];
        }
        const float* wp = wbase + (size_t)cin * 4608;   // 64*72
        #pragma unroll
        for (int j = 0; j < 8; ++j) {
            float a = acc0[j];
            float b = acc1[j];
            #pragma unroll
            for (int t = 0; t < 9; ++t) {
                const float w = wp[t * 8 + j];
                a = fmaf(w, v0[t], a);
                b = fmaf(w, v1[t], b);
            }
            acc0[j] = a;
            acc1[j] = b;
        }
    }

    // coalesced: lane=px contiguous per oc row
    float* dst0 = part2 + ((size_t)blockIdx.z * 512 + ocg * 8) * NPIX + px0;
    #pragma unroll
    for (int j = 0; j < 8; ++j)
        dst0[(size_t)j * NPIX] = acc0[j];
    if (act1) {
        float* dst1 = part2 + ((size_t)blockIdx.z * 512 + ocg * 8) * NPIX + px1;
        #pragma unroll
        for (int j = 0; j < 8; ++j)
            dst1[(size_t)j * NPIX] = acc1[j];
    }
}

// ---------------- reduce partials + bias + leaky (coalesced) ---------------
__global__ __launch_bounds__(256) void reduce_leaky2(
    const float* __restrict__ part2, const float* __restrict__ bias,
    float* __restrict__ feat)
{
    const int oc = blockIdx.y;
    const int px = blockIdx.x * 256 + threadIdx.x;
    if (px >= NPIX) return;
    float s = 0.f;
    #pragma unroll
    for (int k = 0; k < CS; ++k)
        s += part2[((size_t)k * 512 + oc) * NPIX + px];
    s += bias[oc];
    s = (s >= 0.f) ? s : 0.01f * s;
    feat[(size_t)oc * NPIX + px] = s;
}

// ---------------- 1x1 heads: 4-wave cin split + LDS tree reduce ------------
__global__ __launch_bounds__(256) void conv1x1_heads(
    const float* __restrict__ feat,
    const float* __restrict__ rw, const float* __restrict__ rb,
    const float* __restrict__ cw, const float* __restrict__ cb,
    float* __restrict__ regcls)   // (54, 2500)
{
    __shared__ float sAcc[3][18][64];
    const int tid  = threadIdx.x;
    const int lane = tid & 63;
    const int wv   = tid >> 6;
    const int pix0 = blockIdx.x * 64 + lane;
    const bool act = (pix0 < NPIX);
    const int pix  = act ? pix0 : (NPIX - 1);
    const int chunk = blockIdx.y;
    const float* wb; const float* bb; int ocbase;
    if (chunk == 0)      { wb = rw;            bb = rb;      ocbase = 0;  }
    else if (chunk == 1) { wb = rw + 18 * 512; bb = rb + 18; ocbase = 18; }
    else                 { wb = cw;            bb = cb;      ocbase = 36; }

    float acc[18];
    #pragma unroll
    for (int k = 0; k < 18; ++k) acc[k] = 0.f;

    const int c0 = wv * 128;
    for (int cin = c0; cin < c0 + 128; ++cin) {
        const float v = feat[(size_t)cin * NPIX + pix];
        #pragma unroll
        for (int k = 0; k < 18; ++k)
            acc[k] = fmaf(wb[k * 512 + cin], v, acc[k]);
    }
    if (wv > 0) {
        #pragma unroll
        for (int k = 0; k < 18; ++k) sAcc[wv - 1][k][lane] = acc[k];
    }
    __syncthreads();
    if (wv == 0 && act) {
        #pragma unroll
        for (int k = 0; k < 18; ++k) {
            float s = acc[k];
            s += sAcc[0][k][lane];
            s += sAcc[1][k][lane];
            s += sAcc[2][k][lane];
            regcls[(size_t)(ocbase + k) * NPIX + pix] = s + bb[k];
        }
    }
}

// ---------------- decode: anchors, softmax score, sortable key -------------
__global__ __launch_bounds__(256) void decodeK(
    const float* __restrict__ regcls,
    float4* __restrict__ boxes,
    unsigned long long* __restrict__ keys)
{
    const int i = blockIdx.x * 256 + threadIdx.x;
    if (i >= NANCH) {
        if (i < NKEY) keys[i] = 0xFFFFFFFFFFFFFFFFull;  // sentinel: > all keys
        return;
    }
    const int pos = i / 9;
    const int a   = i - pos * 9;
    const int hh  = pos / 50;
    const int wwp = pos - hh * 50;
    const int r = a / 3, s = a - r * 3;

    const float base_s[3] = {128.f, 256.f, 512.f};
    const float sq [3] = {0.70710678118654752440f, 1.0f, 1.41421356237309504880f};
    const float sqi[3] = {1.41421356237309504880f, 1.0f, 0.70710678118654752440f};
    const float hs = base_s[s] * sq[r];
    const float ws = base_s[s] * sqi[r];
    const float cx = (float)(hh * 16 + 8);    // cx indexed by h (reference quirk)
    const float cy = (float)(wwp * 16 + 8);
    const float ax = cx - ws * 0.5f;
    const float ay = cy - hs * 0.5f;

    const float pr0 = regcls[(size_t)(a * 4 + 0) * NPIX + pos];
    const float pr1 = regcls[(size_t)(a * 4 + 1) * NPIX + pos];
    const float pr2 = regcls[(size_t)(a * 4 + 2) * NPIX + pos];
    const float pr3 = regcls[(size_t)(a * 4 + 3) * NPIX + pos];
    const float c0  = regcls[(size_t)(36 + a * 2 + 0) * NPIX + pos];
    const float c1  = regcls[(size_t)(36 + a * 2 + 1) * NPIX + pos];

    const float m  = fmaxf(c0, c1);
    const float e0 = expf(c0 - m);
    const float e1 = expf(c1 - m);
    const float score = e1 / (e0 + e1);

    const float t0 = pr0 + ax;
    const float t1 = pr1 + ay;
    const float hi = 799.0f;
    const float rx1 = fminf(fmaxf(t0, 0.f), hi);
    const float ry1 = fminf(fmaxf(t1, 0.f), hi);
    const float rx2 = fminf(fmaxf((t0 + pr2) + ws, 0.f), hi);
    const float ry2 = fminf(fmaxf((t1 + pr3) + hs, 0.f), hi);
    const float bw = pr2 + ws;
    const float bh = pr3 + hs;
    const bool valid = (bw >= 16.f) && (bh >= 16.f);
    const float sc = valid ? score : -__builtin_inff();

    unsigned u = __float_as_uint(sc);
    u = (u & 0x80000000u) ? ~u : (u | 0x80000000u);  // monotone ascending map
    const unsigned k32 = ~u;                          // descending score
    keys[i]  = ((unsigned long long)k32 << 32) | (unsigned)i;  // tie: asc index
    boxes[i] = make_float4(rx1, ry1, rx2, ry2);
}

// ---------------- O(N^2) rank (stable argsort position) --------------------
__global__ __launch_bounds__(256) void rankK(
    const unsigned long long* __restrict__ keys, int* __restrict__ rank)
{
    const int i = blockIdx.x * 256 + threadIdx.x;
    const unsigned long long my = (i < NANCH) ? keys[i] : 0ull;
    const unsigned long long* kj = keys + blockIdx.y * 2816;
    int cnt = 0;
    for (int t = 0; t < 2816; t += 8) {
        #pragma unroll
        for (int q = 0; q < 8; ++q)
            cnt += (kj[t + q] < my) ? 1 : 0;
    }
    if (i < NANCH) atomicAdd(&rank[i], cnt);
}

__global__ __launch_bounds__(256) void scatterK(
    const float4* __restrict__ boxes, const int* __restrict__ rank,
    float4* __restrict__ sboxes)
{
    const int i = blockIdx.x * 256 + threadIdx.x;
    if (i < NANCH) {
        const int r = rank[i];
        if (r < PRE) sboxes[r] = boxes[i];
    }
}

// ---------------- NMS suppression bitmask (reference bug replicated) -------
__global__ __launch_bounds__(256) void nmsMaskK(
    const float4* __restrict__ sb, unsigned long long* __restrict__ mask)
{
    __shared__ float sx1[JCHUNK], sy1[JCHUNK], sx2[JCHUNK], sy2[JCHUNK], sar[JCHUNK];
    const int tid = threadIdx.x;
    const int jbase = blockIdx.y * JCHUNK;
    for (int t = tid; t < JCHUNK; t += 256) {
        const int j = jbase + t;
        if (j < PRE) {
            const float4 b = sb[j];
            sx1[t] = b.x; sy1[t] = b.y; sx2[t] = b.z; sy2[t] = b.w;
            sar[t] = (b.z - b.x + 1.f) * (b.w - b.y + 1.f);
        } else {
            sx1[t] = 0.f; sy1[t] = 0.f; sx2[t] = -1.f; sy2[t] = 0.f; sar[t] = 0.f;
        }
    }
    __syncthreads();
    const int i = blockIdx.x * 16 + (tid >> 4);
    const float4 bi = sb[i];
    const float x1 = bi.x, y1 = bi.y, x2 = bi.z, y2 = bi.w;
    const float ar = (x2 - x1 + 1.f) * (y2 - y1 + 1.f);
    for (int w = (tid & 15); w < 24; w += 16) {
        unsigned long long bits = 0ull;
        const int l0 = w * 64;
        for (int u = 0; u < 64; ++u) {
            const int j = jbase + l0 + u;
            if (j > i && j < PRE) {
                const int l = l0 + u;
                const float xx1 = fmaxf(x1, sx1[l]);
                const float yy1 = fmaxf(y1, sy1[l]);
                const float xx2 = fminf(x2, sx2[l]);
                const float yy2 = fmaxf(y2, sy2[l]);        // reference bug: max
                const float wv = fmaxf(0.f, xx2 - xx1 + 1.f);
                const float hv = fmaxf(0.f, yy2 - yy1 + 1.f);
                const float inter = wv * hv;
                const float ov = inter / ((ar + sar[l]) - inter);  // precise div
                if (ov > 0.7f) bits |= (1ull << u);
            }
        }
        mask[(size_t)i * MW + blockIdx.y * 24 + w] = bits;
    }
}

// ---------------- word-serial NMS scan + output (single wave) --------------
// Per 64-candidate block g: (1) pure-ALU in-block loop using ONLY the diag
// word (every iteration keeps exactly one box; suppression via diag
// readlanes); (2) batched loads of the ~3 actually-kept rows (<=KSLOT static
// slots + rare overflow), one wait, OR into register-resident rem.
__global__ __launch_bounds__(64) void nmsScanOutK(
    const unsigned long long* __restrict__ mask,
    const float4* __restrict__ sb,
    float* __restrict__ out)
{
    __shared__ int sKept[300];
    __shared__ unsigned long long sKeepW[MASKW];
    const int lane = threadIdx.x;

    unsigned long long rem0 = 0ull, rem1 = 0ull;   // lane l: words l, 64+l
    int cnt = 0;
    int done = 0;

    unsigned long long diag = mask[(size_t)lane * MW + 0];   // block 0 diag

    for (int g = 0; g < MASKW && !done; ++g) {
        // prefetch next block's diagonal word (overlaps this block's work)
        unsigned long long diag_next = 0ull;
        if (g + 1 < MASKW) {
            const int r2 = (g + 1) * 64 + lane;
            if (r2 < PRE) diag_next = mask[(size_t)r2 * MW + (g + 1)];
        }
        // initial suppression word for this block (broadcast from rem)
        unsigned long long cur;
        {
            unsigned lo, hi;
            if (g < 64) {
                lo = __builtin_amdgcn_readlane((unsigned)rem0, g);
                hi = __builtin_amdgcn_readlane((unsigned)(rem0 >> 32), g);
            } else {
                lo = __builtin_amdgcn_readlane((unsigned)rem1, g - 64);
                hi = __builtin_amdgcn_readlane((unsigned)(rem1 >> 32), g - 64);
            }
            cur = ((unsigned long long)hi << 32) | lo;
        }
        const unsigned long long valid =
            (g == MASKW - 1) ? 0x0000FFFFFFFFFFFFull : ~0ull;   // 48 tail bits

        // ---- in-block serial loop: pure ALU, zero memory ops ----
        unsigned long long kb = 0ull;
        for (;;) {
            const unsigned long long nd = (~cur) & valid;
            if (!nd) break;
            const int b = __builtin_ctzll(nd);     // unsuppressed => KEPT
            if (lane == 0 && cnt < 300) sKept[cnt] = g * 64 + b;
            ++cnt;
            kb |= (1ull << b);
            if (cnt >= 300) { done = 1; break; }
            const unsigned dlo = __builtin_amdgcn_readlane((unsigned)diag, b);
            const unsigned dhi = __builtin_amdgcn_readlane((unsigned)(diag >> 32), b);
            cur |= (1ull << b) | (((unsigned long long)dhi << 32) | dlo);
        }
        if (lane == 0) sKeepW[g] = kb;

        // ---- batched kept-row loads: OR their full rows into rem ----
        if (!done && kb) {
            int kbit[KSLOT];
            unsigned long long t = kb;
            #pragma unroll
            for (int s = 0; s < KSLOT; ++s) {
                kbit[s] = t ? __builtin_ctzll(t) : 64;
                t &= t - 1;
            }
            unsigned long long a0 = 0ull, a1 = 0ull;
            #pragma unroll
            for (int s = 0; s < KSLOT; ++s) {
                if (kbit[s] < 64) {                // wave-uniform branch
                    const unsigned long long* pr =
                        mask + (size_t)(g * 64 + kbit[s]) * MW;
                    a0 |= pr[lane];
                    a1 |= (lane < MASKW - 64) ? pr[64 + lane] : 0ull;
                }
            }
            while (t) {                             // >KSLOT overflow (rare)
                const int b = __builtin_ctzll(t); t &= t - 1;
                const unsigned long long* pr = mask + (size_t)(g * 64 + b) * MW;
                a0 |= pr[lane];
                a1 |= (lane < MASKW - 64) ? pr[64 + lane] : 0ull;
            }
            rem0 |= a0;
            rem1 |= a1;
        }
        diag = diag_next;
    }

    __syncthreads();

    if (cnt < 300) {                                 // filler: unkept, asc index
        int c = cnt;
        for (int g = 0; g < MASKW && c < 300; ++g) {
            const unsigned long long valid =
                (g == MASKW - 1) ? 0x0000FFFFFFFFFFFFull : ~0ull;
            unsigned long long u = (~sKeepW[g]) & valid;
            while (u && c < 300) {
                const int b = __builtin_ctzll(u); u &= u - 1;
                if (lane == 0) sKept[c] = g * 64 + b;
                ++c;
            }
        }
    }
    __syncthreads();

    for (int s = lane; s < 300; s += 64) {
        const float4 b = sb[sKept[s]];
        out[s * 4 + 0] = b.x;
        out[s * 4 + 1] = b.y;
        out[s * 4 + 2] = b.z - b.x + 1.0f;
        out[s * 4 + 3] = b.w - b.y + 1.0f;
    }
}

// ---------------------------------------------------------------------------
extern "C" void kernel_launch(void* const* d_in, const int* in_sizes, int n_in,
                              void* d_out, int out_size, void* d_ws, size_t ws_size,
                              hipStream_t stream)
{
    (void)in_sizes; (void)n_in; (void)out_size; (void)ws_size;
    const float* x   = (const float*)d_in[0] + (size_t)7 * 512 * NPIX; // batch 7
    const float* cw3 = (const float*)d_in[1];
    const float* cb3 = (const float*)d_in[2];
    const float* rw  = (const float*)d_in[3];
    const float* rb  = (const float*)d_in[4];
    const float* clw = (const float*)d_in[5];
    const float* clb = (const float*)d_in[6];
    float* out = (float*)d_out;

    char* p = (char*)d_ws;
    auto alloc = [&](size_t n) { char* r = p; p += (n + 255) & ~(size_t)255; return r; };
    float*  part2  = (float*)alloc((size_t)CS * 512 * NPIX * 4);  // 41 MB
    float*  wtV    = (float*)alloc((size_t)4608 * 512 * 4);       // 9.4 MB
    float*  xpad   = (float*)alloc((size_t)512 * PSL * 4);        // 5.5 MB
    float*  feat   = (float*)alloc((size_t)512 * NPIX * 4);       // 5.12 MB
    float*  regcls = (float*)alloc((size_t)54 * NPIX * 4);        // 0.54 MB
    float4* boxes  = (float4*)alloc((size_t)NANCH * 16);          // 0.36 MB
    unsigned long long* keys = (unsigned long long*)alloc((size_t)NKEY * 8);
    int*    rank   = (int*)alloc((size_t)NANCH * 4);
    float4* sboxes = (float4*)alloc((size_t)PRE * 16);
    unsigned long long* mask = (unsigned long long*)alloc((size_t)PRE * MW * 8); // 4.6 MB

    hipMemsetAsync(rank, 0, (size_t)NANCH * 4, stream);
    prepK         <<<1088, 256, 0, stream>>>(x, cw3, xpad, wtV);
    conv3x3_v9    <<<dim3(64, 5, CS), 256, 0, stream>>>(xpad, wtV, part2);
    reduce_leaky2 <<<dim3(10, 512), 256, 0, stream>>>(part2, cb3, feat);
    conv1x1_heads <<<dim3(40, 3), 256, 0, stream>>>(feat, rw, rb, clw, clb, regcls);
    decodeK       <<<88, 256, 0, stream>>>(regcls, boxes, keys);
    rankK         <<<dim3(88, 8), 256, 0, stream>>>(keys, rank);
    scatterK      <<<88, 256, 0, stream>>>(boxes, rank, sboxes);
    nmsMaskK      <<<dim3(375, 4), 256, 0, stream>>>(sboxes, mask);
    nmsScanOutK   <<<1, 64, 0, stream>>>(mask, sboxes, out);
}